// Round 2
// baseline (531.599 us; speedup 1.0000x reference)
//
#include <hip/hip_runtime.h>

typedef __attribute__((ext_vector_type(8))) short short8;
typedef __attribute__((ext_vector_type(4))) float f32x4;

__device__ __forceinline__ unsigned short f2bf(float f){
  unsigned u = __float_as_uint(f);
  u += 0x7fffu + ((u >> 16) & 1u);
  return (unsigned short)(u >> 16);
}
__device__ __forceinline__ float bf2f(unsigned short h){
  return __uint_as_float(((unsigned)h) << 16);
}

// ---------- elementwise: fp32 -> bf16 hi/lo split ----------
__global__ __launch_bounds__(256) void split4_k(const float4* __restrict__ in,
                                                ushort4* __restrict__ hi,
                                                ushort4* __restrict__ lo){
  int i = blockIdx.x * 256 + threadIdx.x;
  float4 v = in[i];
  float f[4] = {v.x, v.y, v.z, v.w};
  unsigned short hs[4], ls[4];
#pragma unroll
  for (int j = 0; j < 4; j++){ hs[j] = f2bf(f[j]); ls[j] = f2bf(f[j] - bf2f(hs[j])); }
  hi[i] = make_ushort4(hs[0], hs[1], hs[2], hs[3]);
  lo[i] = make_ushort4(ls[0], ls[1], ls[2], ls[3]);
}

// ---------- elementwise: fp32 -> bf16 ----------
__global__ __launch_bounds__(256) void conv4_k(const float4* __restrict__ in,
                                               ushort4* __restrict__ hi){
  int i = blockIdx.x * 256 + threadIdx.x;
  float4 v = in[i];
  hi[i] = make_ushort4(f2bf(v.x), f2bf(v.y), f2bf(v.z), f2bf(v.w));
}

// ---------- mask dtype detection ----------
// flag=1: 4-byte elements (int32 0/1 or fp32 0.0/1.0 -> nonzero test on u32 works)
// flag=0: 1-byte elements (numpy bool / uint8)
__global__ void mask_detect(const unsigned int* __restrict__ m, int* __restrict__ flag){
  if (threadIdx.x == 0 && blockIdx.x == 0){
    int ok = 1;
#pragma unroll
    for (int j = 0; j < 16; j++){
      unsigned v = m[j];
      if (v != 0u && v != 1u && v != 0x3f800000u) ok = 0;
    }
    *flag = ok;
  }
}

// ---------- bf16 transpose: V[b][2048][1024] -> VT[b][1024][2048] ----------
__global__ __launch_bounds__(256) void transpose_v(const unsigned short* __restrict__ V,
                                                   unsigned short* __restrict__ VT){
  __shared__ unsigned short t[32][33];
  const int b = blockIdx.z;
  const int t0 = blockIdx.x * 32, d0 = blockIdx.y * 32;
  const int x = threadIdx.x & 31, y = threadIdx.x >> 5;   // y: 0..7
  const long Vb = (long)b * 2048 * 1024, Tb = (long)b * 1024 * 2048;
#pragma unroll
  for (int i = 0; i < 4; i++){
    int r = y + i * 8;
    t[r][x] = V[Vb + (long)(t0 + r) * 1024 + d0 + x];
  }
  __syncthreads();
#pragma unroll
  for (int i = 0; i < 4; i++){
    int r = y + i * 8;
    VT[Tb + (long)(d0 + r) * 2048 + t0 + x] = t[x][r];
  }
}

// ---------- row softmax over 2048 fp32 -> bf16 P ----------
__global__ __launch_bounds__(256) void softmax2048(const float* __restrict__ S,
                                                   unsigned short* __restrict__ P){
  const long row = blockIdx.x;
  const float* s = S + row * 2048;
  unsigned short* p = P + row * 2048;
  const int tid = threadIdx.x;
  float v[8];
  float m = -1e30f;
#pragma unroll
  for (int i = 0; i < 8; i++){ v[i] = s[tid + i * 256]; m = fmaxf(m, v[i]); }
#pragma unroll
  for (int o = 32; o; o >>= 1) m = fmaxf(m, __shfl_xor(m, o));
  __shared__ float rm[4], rs[4];
  if ((tid & 63) == 0) rm[tid >> 6] = m;
  __syncthreads();
  m = fmaxf(fmaxf(rm[0], rm[1]), fmaxf(rm[2], rm[3]));
  float sum = 0.f;
#pragma unroll
  for (int i = 0; i < 8; i++){ v[i] = __expf(v[i] - m); sum += v[i]; }
#pragma unroll
  for (int o = 32; o; o >>= 1) sum += __shfl_xor(sum, o);
  if ((tid & 63) == 0) rs[tid >> 6] = sum;
  __syncthreads();
  sum = rs[0] + rs[1] + rs[2] + rs[3];
  const float inv = 1.0f / sum;
#pragma unroll
  for (int i = 0; i < 8; i++) p[tid + i * 256] = f2bf(v[i] * inv);
}

// ---------- GEMM: C(MxN) = A(MxK) @ B(NxK)^T  (B^T form, both row-major over K) ----------
// SPLIT: A,B given as bf16 hi/lo pairs -> 3 MFMAs (hi*hi + hi*lo + lo*hi), ~fp32 accuracy.
// EPI: 0 = fp32 out (+bias)
//      1 = fp32 out with key-mask -> -1e30 (scores)
//      2 = bf16 out (+bias)
//      3 = bf16 hi/lo out (+bias)
#define GLL(gp, ldsoff) \
  __builtin_amdgcn_global_load_lds((const __attribute__((address_space(1))) void*)(gp), \
                                   (__attribute__((address_space(3))) void*)&lds[ldsoff], 16, 0, 0)

template<bool SPLIT, int EPI>
__global__ __launch_bounds__(256)
void gemm_bt(const unsigned short* __restrict__ Ah, const unsigned short* __restrict__ Al,
             const unsigned short* __restrict__ Bh, const unsigned short* __restrict__ Bl,
             int lda, int ldb, int K,
             const float* __restrict__ bias, const void* __restrict__ mask,
             const int* __restrict__ maskFlag,
             void* __restrict__ out0, void* __restrict__ out1, int ldc,
             long aBS, long bBS, long oBS, int maskBS)
{
  constexpr int NT = SPLIT ? 4 : 2;
  __shared__ short lds[NT * 128 * 32];

  const int z = blockIdx.z;
  const long zA = (long)z * aBS, zB = (long)z * bBS;
  const int tid = threadIdx.x;
  const int lane = tid & 63, wid = tid >> 6;
  const int wr = wid >> 1, wc = wid & 1;
  const int fr = lane & 15, fk = lane >> 4;
  const int brow = blockIdx.x * 128, bcol = blockIdx.y * 128;

  f32x4 acc[4][4];
  const f32x4 fzero = {0.f, 0.f, 0.f, 0.f};
#pragma unroll
  for (int i = 0; i < 4; i++)
#pragma unroll
    for (int j = 0; j < 4; j++) acc[i][j] = fzero;

  const int offA = (wr * 64 + fr) * 32 + fk * 8;   // element offset in A tile
  const int offB = (wc * 64 + fr) * 32 + fk * 8;   // element offset in B tile
  const int srow = tid >> 2;                       // staging row 0..63 (pass 0)
  const int sck  = (tid & 3) * 8;                  // staging col (elements)

  for (int k0 = 0; k0 < K; k0 += 32) {
    __syncthreads();
    {
      const unsigned short* gA = Ah + zA + (long)(brow + srow) * lda + k0 + sck;
      GLL(gA, tid * 8);
      GLL(gA + (long)64 * lda, (256 + tid) * 8);
      const unsigned short* gB = Bh + zB + (long)(bcol + srow) * ldb + k0 + sck;
      GLL(gB, 4096 + tid * 8);
      GLL(gB + (long)64 * ldb, 4096 + (256 + tid) * 8);
      if constexpr (SPLIT) {
        const unsigned short* gAl = Al + zA + (long)(brow + srow) * lda + k0 + sck;
        GLL(gAl, 8192 + tid * 8);
        GLL(gAl + (long)64 * lda, 8192 + (256 + tid) * 8);
        const unsigned short* gBl = Bl + zB + (long)(bcol + srow) * ldb + k0 + sck;
        GLL(gBl, 12288 + tid * 8);
        GLL(gBl + (long)64 * ldb, 12288 + (256 + tid) * 8);
      }
    }
    __syncthreads();

    short8 ah[4], bh[4];
#pragma unroll
    for (int i = 0; i < 4; i++){
      ah[i] = *(const short8*)&lds[offA + i * 512];
      bh[i] = *(const short8*)&lds[4096 + offB + i * 512];
    }
    if constexpr (SPLIT) {
      short8 al[4], bl[4];
#pragma unroll
      for (int i = 0; i < 4; i++){
        al[i] = *(const short8*)&lds[8192 + offA + i * 512];
        bl[i] = *(const short8*)&lds[12288 + offB + i * 512];
      }
#pragma unroll
      for (int mi = 0; mi < 4; mi++)
#pragma unroll
        for (int ni = 0; ni < 4; ni++){
          f32x4 c = acc[mi][ni];
          c = __builtin_amdgcn_mfma_f32_16x16x32_bf16(ah[mi], bh[ni], c, 0, 0, 0);
          c = __builtin_amdgcn_mfma_f32_16x16x32_bf16(ah[mi], bl[ni], c, 0, 0, 0);
          c = __builtin_amdgcn_mfma_f32_16x16x32_bf16(al[mi], bh[ni], c, 0, 0, 0);
          acc[mi][ni] = c;
        }
    } else {
#pragma unroll
      for (int mi = 0; mi < 4; mi++)
#pragma unroll
        for (int ni = 0; ni < 4; ni++)
          acc[mi][ni] = __builtin_amdgcn_mfma_f32_16x16x32_bf16(ah[mi], bh[ni], acc[mi][ni], 0, 0, 0);
    }
  }

  // epilogue: C/D frag layout col=lane&15, row=(lane>>4)*4+r  [m89-verified]
  const long zO = (long)z * oBS;
  int mflag = 0;
  if constexpr (EPI == 1) mflag = *maskFlag;
#pragma unroll
  for (int mi = 0; mi < 4; mi++){
#pragma unroll
    for (int ni = 0; ni < 4; ni++){
      const int col = bcol + wc * 64 + ni * 16 + fr;
      float bv = 0.f;
      if constexpr (EPI != 1) { if (bias) bv = bias[col]; }
      bool msk = false;
      if constexpr (EPI == 1) {
        msk = mflag ? (((const int*)mask)[(long)z * maskBS + col] != 0)
                    : (((const unsigned char*)mask)[(long)z * maskBS + col] != 0);
      }
#pragma unroll
      for (int r = 0; r < 4; r++){
        const int row = brow + wr * 64 + mi * 16 + fk * 4 + r;
        float v = acc[mi][ni][r] + bv;
        const long idx = zO + (long)row * ldc + col;
        if constexpr (EPI == 0) {
          ((float*)out0)[idx] = v;
        } else if constexpr (EPI == 1) {
          ((float*)out0)[idx] = msk ? -1e30f : v;
        } else if constexpr (EPI == 2) {
          ((unsigned short*)out0)[idx] = f2bf(v);
        } else {
          unsigned short h = f2bf(v);
          ((unsigned short*)out0)[idx] = h;
          ((unsigned short*)out1)[idx] = f2bf(v - bf2f(h));
        }
      }
    }
  }
}

extern "C" void kernel_launch(void* const* d_in, const int* in_sizes, int n_in,
                              void* d_out, int out_size, void* d_ws, size_t ws_size,
                              hipStream_t stream)
{
  (void)in_sizes; (void)n_in; (void)out_size; (void)ws_size;
  const float* query = (const float*)d_in[0];   // (4,2048,1024)
  const float* key   = (const float*)d_in[1];   // (4,2048,1024)
  const void*  kmask = d_in[2];                 // (4,2048) bool -> dtype detected on device
  const float* Wq    = (const float*)d_in[3];   // (1024,1024)
  const float* bq    = (const float*)d_in[4];
  const float* Wk    = (const float*)d_in[5];   // (2048,1024)
  const float* bk    = (const float*)d_in[6];
  const float* Wfc   = (const float*)d_in[7];   // (1024,1024)
  const float* bfc   = (const float*)d_in[8];
  float* out = (float*)d_out;

  char* ws = (char*)d_ws;
  size_t o = 0;
  auto take = [&](size_t bytes)->char*{
    char* p = ws + o;
    o += (bytes + 255) & ~(size_t)255;
    return p;
  };
  const size_t SZ_BF = (size_t)8192 * 1024 * 2;     // 16.78 MB (8192x1024 bf16)

  int* maskFlag            = (int*)take(256);
  unsigned short* query_hi = (unsigned short*)take(SZ_BF);
  unsigned short* query_lo = (unsigned short*)take(SZ_BF);
  unsigned short* key_hi   = (unsigned short*)take(SZ_BF);
  unsigned short* key_lo   = (unsigned short*)take(SZ_BF);
  unsigned short* Wq_hi    = (unsigned short*)take((size_t)1024 * 1024 * 2);
  unsigned short* Wq_lo    = (unsigned short*)take((size_t)1024 * 1024 * 2);
  unsigned short* Wk_hi    = (unsigned short*)take((size_t)2048 * 1024 * 2);
  unsigned short* Wk_lo    = (unsigned short*)take((size_t)2048 * 1024 * 2);
  unsigned short* Wfc_b    = (unsigned short*)take((size_t)1024 * 1024 * 2);
  unsigned short* Q_hi     = (unsigned short*)take(SZ_BF);
  unsigned short* Q_lo     = (unsigned short*)take(SZ_BF);
  unsigned short* K_hi     = (unsigned short*)take(SZ_BF);
  unsigned short* K_lo     = (unsigned short*)take(SZ_BF);
  unsigned short* V        = (unsigned short*)take(SZ_BF);
  unsigned short* VT       = (unsigned short*)take(SZ_BF);
  float*          S        = (float*)take((size_t)8192 * 2048 * 4);  // 67.1 MB
  // aliases over dead regions:
  unsigned short* P = query_hi;   // needs 33.55 MB = query_hi+query_lo (contiguous)
  unsigned short* O = key_hi;     // needs 16.78 MB

  mask_detect<<<1, 64, 0, stream>>>((const unsigned int*)kmask, maskFlag);

  split4_k<<<8192, 256, 0, stream>>>((const float4*)query, (ushort4*)query_hi, (ushort4*)query_lo);
  split4_k<<<8192, 256, 0, stream>>>((const float4*)key,   (ushort4*)key_hi,   (ushort4*)key_lo);
  split4_k<<<1024, 256, 0, stream>>>((const float4*)Wq,    (ushort4*)Wq_hi,    (ushort4*)Wq_lo);
  split4_k<<<2048, 256, 0, stream>>>((const float4*)Wk,    (ushort4*)Wk_hi,    (ushort4*)Wk_lo);
  conv4_k <<<1024, 256, 0, stream>>>((const float4*)Wfc,   (ushort4*)Wfc_b);

  // Q = query @ Wq^T + bq  -> hi/lo   (8192x1024, K=1024)
  gemm_bt<true, 3><<<dim3(64, 8, 1), 256, 0, stream>>>(
      query_hi, query_lo, Wq_hi, Wq_lo, 1024, 1024, 1024,
      bq, nullptr, nullptr, Q_hi, Q_lo, 1024, 0, 0, 0, 0);

  // K = key @ Wk[0:1024]^T + bk[0:1024] -> hi/lo
  gemm_bt<true, 3><<<dim3(64, 8, 1), 256, 0, stream>>>(
      key_hi, key_lo, Wk_hi, Wk_lo, 1024, 1024, 1024,
      bk, nullptr, nullptr, K_hi, K_lo, 1024, 0, 0, 0, 0);

  // V = key @ Wk[1024:2048]^T + bk[1024:2048] -> bf16
  gemm_bt<true, 2><<<dim3(64, 8, 1), 256, 0, stream>>>(
      key_hi, key_lo, Wk_hi + (size_t)1024 * 1024, Wk_lo + (size_t)1024 * 1024, 1024, 1024, 1024,
      bk + 1024, nullptr, nullptr, V, nullptr, 1024, 0, 0, 0, 0);

  transpose_v<<<dim3(64, 32, 4), 256, 0, stream>>>(V, VT);

  // scores: per batch S = Q @ K^T, masked  (2048x2048, K=1024)
  gemm_bt<true, 1><<<dim3(16, 16, 4), 256, 0, stream>>>(
      Q_hi, Q_lo, K_hi, K_lo, 1024, 1024, 1024,
      nullptr, kmask, maskFlag, S, nullptr, 2048,
      (long)2048 * 1024, (long)2048 * 1024, (long)2048 * 2048, 2048);

  softmax2048<<<8192, 256, 0, stream>>>(S, P);

  // O = P @ V  (per batch 2048x1024, K=2048; B = VT rows are V columns)
  gemm_bt<false, 2><<<dim3(16, 8, 4), 256, 0, stream>>>(
      P, nullptr, VT, nullptr, 2048, 2048, 2048,
      nullptr, nullptr, nullptr, O, nullptr, 1024,
      (long)2048 * 2048, (long)1024 * 2048, (long)2048 * 1024, 0);

  // out = O @ Wfc^T + bfc  (8192x1024, K=1024, fp32 out)
  gemm_bt<false, 0><<<dim3(64, 8, 1), 256, 0, stream>>>(
      O, nullptr, Wfc_b, nullptr, 1024, 1024, 1024,
      bfc, nullptr, nullptr, out, nullptr, 1024, 0, 0, 0, 0);
}

// Round 3
// 403.167 us; speedup vs baseline: 1.3186x; 1.3186x over previous
//
#include <hip/hip_runtime.h>

typedef __attribute__((ext_vector_type(8))) _Float16 half8;
typedef __attribute__((ext_vector_type(4))) _Float16 half4;
typedef __attribute__((ext_vector_type(4))) float f32x4;

// ---------- elementwise: fp32 -> fp16 ----------
__global__ __launch_bounds__(256) void conv4_k(const float4* __restrict__ in,
                                               half4* __restrict__ out){
  int i = blockIdx.x * 256 + threadIdx.x;
  float4 v = in[i];
  half4 h = { (_Float16)v.x, (_Float16)v.y, (_Float16)v.z, (_Float16)v.w };
  out[i] = h;
}

// ---------- mask dtype detection ----------
// flag=1: 4-byte elements (int32 0/1 or fp32 0.0/1.0 -> nonzero test on u32 works)
// flag=0: 1-byte elements (numpy bool / uint8)
__global__ void mask_detect(const unsigned int* __restrict__ m, int* __restrict__ flag){
  if (threadIdx.x == 0 && blockIdx.x == 0){
    int ok = 1;
#pragma unroll
    for (int j = 0; j < 16; j++){
      unsigned v = m[j];
      if (v != 0u && v != 1u && v != 0x3f800000u) ok = 0;
    }
    *flag = ok;
  }
}

// ---------- row softmax over 2048 fp32 -> fp16 P ----------
__global__ __launch_bounds__(256) void softmax2048(const float* __restrict__ S,
                                                   _Float16* __restrict__ P){
  const long row = blockIdx.x;
  const float* s = S + row * 2048;
  _Float16* p = P + row * 2048;
  const int tid = threadIdx.x;
  float v[8];
  float m = -1e30f;
#pragma unroll
  for (int i = 0; i < 8; i++){ v[i] = s[tid + i * 256]; m = fmaxf(m, v[i]); }
#pragma unroll
  for (int o = 32; o; o >>= 1) m = fmaxf(m, __shfl_xor(m, o));
  __shared__ float rm[4], rs[4];
  if ((tid & 63) == 0) rm[tid >> 6] = m;
  __syncthreads();
  m = fmaxf(fmaxf(rm[0], rm[1]), fmaxf(rm[2], rm[3]));
  float sum = 0.f;
#pragma unroll
  for (int i = 0; i < 8; i++){ v[i] = __expf(v[i] - m); sum += v[i]; }
#pragma unroll
  for (int o = 32; o; o >>= 1) sum += __shfl_xor(sum, o);
  if ((tid & 63) == 0) rs[tid >> 6] = sum;
  __syncthreads();
  sum = rs[0] + rs[1] + rs[2] + rs[3];
  const float inv = 1.0f / sum;
#pragma unroll
  for (int i = 0; i < 8; i++) p[tid + i * 256] = (_Float16)(v[i] * inv);
}

// ---------- GEMM: C(MxN) = A(MxK) @ B(NxK)^T  (fp16 in, fp32 accum) ----------
// EPI: 0 = fp32 out (+bias)
//      1 = fp32 out with key-mask -> -1e30 (scores)
//      2 = fp16 out (+bias)
//      4 = fp16 out TRANSPOSED per batch: VT[b][col][row&2047]  (+bias)
#define GLL(gp, ldsoff) \
  __builtin_amdgcn_global_load_lds((const __attribute__((address_space(1))) void*)(gp), \
                                   (__attribute__((address_space(3))) void*)&lds[ldsoff], 16, 0, 0)

template<int EPI>
__global__ __launch_bounds__(256)
void gemm_bt(const unsigned short* __restrict__ A, const unsigned short* __restrict__ B,
             int lda, int ldb, int K,
             const float* __restrict__ bias, const void* __restrict__ mask,
             const int* __restrict__ maskFlag,
             void* __restrict__ out0, int ldc,
             long aBS, long bBS, long oBS, int maskBS)
{
  __shared__ short lds[2 * 128 * 32];

  const int z = blockIdx.z;
  const long zA = (long)z * aBS, zB = (long)z * bBS;
  const int tid = threadIdx.x;
  const int lane = tid & 63, wid = tid >> 6;
  const int wr = wid >> 1, wc = wid & 1;
  const int fr = lane & 15, fk = lane >> 4;
  const int brow = blockIdx.x * 128, bcol = blockIdx.y * 128;

  f32x4 acc[4][4];
  const f32x4 fzero = {0.f, 0.f, 0.f, 0.f};
#pragma unroll
  for (int i = 0; i < 4; i++)
#pragma unroll
    for (int j = 0; j < 4; j++) acc[i][j] = fzero;

  const int offA = (wr * 64 + fr) * 32 + fk * 8;   // element offset in A tile
  const int offB = (wc * 64 + fr) * 32 + fk * 8;   // element offset in B tile
  const int srow = tid >> 2;                       // staging row 0..63
  const int sck  = (tid & 3) * 8;                  // staging col (elements)

  for (int k0 = 0; k0 < K; k0 += 32) {
    __syncthreads();
    {
      const unsigned short* gA = A + zA + (long)(brow + srow) * lda + k0 + sck;
      GLL(gA, tid * 8);
      GLL(gA + (long)64 * lda, (256 + tid) * 8);
      const unsigned short* gB = B + zB + (long)(bcol + srow) * ldb + k0 + sck;
      GLL(gB, 4096 + tid * 8);
      GLL(gB + (long)64 * ldb, 4096 + (256 + tid) * 8);
    }
    __syncthreads();

    half8 a[4], b[4];
#pragma unroll
    for (int i = 0; i < 4; i++){
      a[i] = *(const half8*)&lds[offA + i * 512];
      b[i] = *(const half8*)&lds[4096 + offB + i * 512];
    }
#pragma unroll
    for (int mi = 0; mi < 4; mi++)
#pragma unroll
      for (int ni = 0; ni < 4; ni++)
        acc[mi][ni] = __builtin_amdgcn_mfma_f32_16x16x32_f16(a[mi], b[ni], acc[mi][ni], 0, 0, 0);
  }

  // epilogue: C/D frag layout col=lane&15, row=(lane>>4)*4+r  [m89-verified]
  const long zO = (long)z * oBS;
  int mflag = 0;
  if constexpr (EPI == 1) mflag = *maskFlag;
#pragma unroll
  for (int mi = 0; mi < 4; mi++){
#pragma unroll
    for (int ni = 0; ni < 4; ni++){
      const int col = bcol + wc * 64 + ni * 16 + fr;
      float bv = 0.f;
      if constexpr (EPI != 1) { if (bias) bv = bias[col]; }
      bool msk = false;
      if constexpr (EPI == 1) {
        msk = mflag ? (((const int*)mask)[(long)z * maskBS + col] != 0)
                    : (((const unsigned char*)mask)[(long)z * maskBS + col] != 0);
      }
#pragma unroll
      for (int r = 0; r < 4; r++){
        const int row = brow + wr * 64 + mi * 16 + fk * 4 + r;
        float v = acc[mi][ni][r] + bv;
        if constexpr (EPI == 0) {
          ((float*)out0)[zO + (long)row * ldc + col] = v;
        } else if constexpr (EPI == 1) {
          ((float*)out0)[zO + (long)row * ldc + col] = msk ? -1e30f : v;
        } else if constexpr (EPI == 2) {
          ((_Float16*)out0)[zO + (long)row * ldc + col] = (_Float16)v;
        } else {
          // transposed per-batch store: VT[b][col][t], b=row>>11, t=row&2047
          const int bb = row >> 11, t = row & 2047;
          ((_Float16*)out0)[(long)bb * 2048 * 1024 + (long)col * 2048 + t] = (_Float16)v;
        }
      }
    }
  }
}

extern "C" void kernel_launch(void* const* d_in, const int* in_sizes, int n_in,
                              void* d_out, int out_size, void* d_ws, size_t ws_size,
                              hipStream_t stream)
{
  (void)in_sizes; (void)n_in; (void)out_size; (void)ws_size;
  const float* query = (const float*)d_in[0];   // (4,2048,1024)
  const float* key   = (const float*)d_in[1];   // (4,2048,1024)
  const void*  kmask = d_in[2];                 // (4,2048) bool -> dtype detected on device
  const float* Wq    = (const float*)d_in[3];   // (1024,1024)
  const float* bq    = (const float*)d_in[4];
  const float* Wk    = (const float*)d_in[5];   // (2048,1024)
  const float* bk    = (const float*)d_in[6];
  const float* Wfc   = (const float*)d_in[7];   // (1024,1024)
  const float* bfc   = (const float*)d_in[8];
  float* out = (float*)d_out;

  char* ws = (char*)d_ws;
  size_t o = 0;
  auto take = [&](size_t bytes)->char*{
    char* p = ws + o;
    o += (bytes + 255) & ~(size_t)255;
    return p;
  };
  const size_t SZ_H = (size_t)8192 * 1024 * 2;      // 16.78 MB (8192x1024 fp16)

  int* maskFlag           = (int*)take(256);
  unsigned short* query_h = (unsigned short*)take(SZ_H);
  unsigned short* key_h   = (unsigned short*)take(SZ_H);
  unsigned short* Wq_h    = (unsigned short*)take((size_t)1024 * 1024 * 2);
  unsigned short* Wk_h    = (unsigned short*)take((size_t)2048 * 1024 * 2);
  unsigned short* Wfc_h   = (unsigned short*)take((size_t)1024 * 1024 * 2);
  unsigned short* Q       = (unsigned short*)take(SZ_H);
  unsigned short* K       = (unsigned short*)take(SZ_H);
  unsigned short* VT      = (unsigned short*)take(SZ_H);
  unsigned short* O       = (unsigned short*)take(SZ_H);
  float*          S       = (float*)take((size_t)8192 * 2048 * 4);   // 67.1 MB
  unsigned short* P       = (unsigned short*)take((size_t)8192 * 2048 * 2); // 33.6 MB

  mask_detect<<<1, 64, 0, stream>>>((const unsigned int*)kmask, maskFlag);

  conv4_k<<<8192, 256, 0, stream>>>((const float4*)query, (half4*)query_h);
  conv4_k<<<8192, 256, 0, stream>>>((const float4*)key,   (half4*)key_h);
  conv4_k<<<1024, 256, 0, stream>>>((const float4*)Wq,    (half4*)Wq_h);
  conv4_k<<<2048, 256, 0, stream>>>((const float4*)Wk,    (half4*)Wk_h);
  conv4_k<<<1024, 256, 0, stream>>>((const float4*)Wfc,   (half4*)Wfc_h);

  // Q = query @ Wq^T + bq   (8192x1024, K=1024) -> fp16
  gemm_bt<2><<<dim3(64, 8, 1), 256, 0, stream>>>(
      query_h, Wq_h, 1024, 1024, 1024,
      bq, nullptr, nullptr, Q, 1024, 0, 0, 0, 0);

  // K = key @ Wk[0:1024]^T + bk[0:1024] -> fp16
  gemm_bt<2><<<dim3(64, 8, 1), 256, 0, stream>>>(
      key_h, Wk_h, 1024, 1024, 1024,
      bk, nullptr, nullptr, K, 1024, 0, 0, 0, 0);

  // V = key @ Wk[1024:2048]^T + bk[1024:2048] -> VT (transposed per batch) fp16
  gemm_bt<4><<<dim3(64, 8, 1), 256, 0, stream>>>(
      key_h, Wk_h + (size_t)1024 * 1024, 1024, 1024, 1024,
      bk + 1024, nullptr, nullptr, VT, 0, 0, 0, 0, 0);

  // scores: per batch S = Q @ K^T, masked  (2048x2048, K=1024) -> fp32
  gemm_bt<1><<<dim3(16, 16, 4), 256, 0, stream>>>(
      Q, K, 1024, 1024, 1024,
      nullptr, kmask, maskFlag, S, 2048,
      (long)2048 * 1024, (long)2048 * 1024, (long)2048 * 2048, 2048);

  softmax2048<<<8192, 256, 0, stream>>>(S, (_Float16*)P);

  // O = P @ V  (per batch 2048x1024, K=2048; B = VT) -> fp16
  gemm_bt<2><<<dim3(16, 8, 4), 256, 0, stream>>>(
      P, VT, 2048, 2048, 2048,
      nullptr, nullptr, nullptr, O, 1024,
      (long)2048 * 2048, (long)1024 * 2048, (long)2048 * 1024, 0);

  // out = O @ Wfc^T + bfc  (8192x1024, K=1024) -> fp32
  gemm_bt<0><<<dim3(64, 8, 1), 256, 0, stream>>>(
      O, Wfc_h, 1024, 1024, 1024,
      bfc, nullptr, nullptr, out, 1024, 0, 0, 0, 0);
}

// Round 4
// 361.957 us; speedup vs baseline: 1.4687x; 1.1139x over previous
//
#include <hip/hip_runtime.h>

typedef __attribute__((ext_vector_type(8))) _Float16 half8;
typedef __attribute__((ext_vector_type(4))) _Float16 half4;
typedef __attribute__((ext_vector_type(4))) float f32x4;

// ---------- elementwise: fp32 -> fp16 ----------
__global__ __launch_bounds__(256) void conv4_k(const float4* __restrict__ in,
                                               half4* __restrict__ out){
  int i = blockIdx.x * 256 + threadIdx.x;
  float4 v = in[i];
  half4 h = { (_Float16)v.x, (_Float16)v.y, (_Float16)v.z, (_Float16)v.w };
  out[i] = h;
}

// ---------- mask dtype detection ----------
// flag=1: 4-byte elements (int32 0/1 or fp32 0.0/1.0 -> nonzero test on u32 works)
// flag=0: 1-byte elements (numpy bool / uint8)
__global__ void mask_detect(const unsigned int* __restrict__ m, int* __restrict__ flag){
  if (threadIdx.x == 0 && blockIdx.x == 0){
    int ok = 1;
#pragma unroll
    for (int j = 0; j < 16; j++){
      unsigned v = m[j];
      if (v != 0u && v != 1u && v != 0x3f800000u) ok = 0;
    }
    *flag = ok;
  }
}

// ---------- row softmax over 2048 fp32 -> fp16 P ----------
__global__ __launch_bounds__(256) void softmax2048(const float* __restrict__ S,
                                                   _Float16* __restrict__ P){
  const long row = blockIdx.x;
  const float* s = S + row * 2048;
  _Float16* p = P + row * 2048;
  const int tid = threadIdx.x;
  float v[8];
  float m = -1e30f;
#pragma unroll
  for (int i = 0; i < 8; i++){ v[i] = s[tid + i * 256]; m = fmaxf(m, v[i]); }
#pragma unroll
  for (int o = 32; o; o >>= 1) m = fmaxf(m, __shfl_xor(m, o));
  __shared__ float rm[4], rs[4];
  if ((tid & 63) == 0) rm[tid >> 6] = m;
  __syncthreads();
  m = fmaxf(fmaxf(rm[0], rm[1]), fmaxf(rm[2], rm[3]));
  float sum = 0.f;
#pragma unroll
  for (int i = 0; i < 8; i++){ v[i] = __expf(v[i] - m); sum += v[i]; }
#pragma unroll
  for (int o = 32; o; o >>= 1) sum += __shfl_xor(sum, o);
  if ((tid & 63) == 0) rs[tid >> 6] = sum;
  __syncthreads();
  sum = rs[0] + rs[1] + rs[2] + rs[3];
  const float inv = 1.0f / sum;
#pragma unroll
  for (int i = 0; i < 8; i++) p[tid + i * 256] = (_Float16)(v[i] * inv);
}

// ---------- GEMM: C(MxN) = A(MxK) @ B(NxK)^T  (fp16 in, fp32 accum) ----------
// 2-phase double-buffered K-loop (T3-minimum): issue next tile's global_load_lds
// into buf^1 BEFORE computing current tile from buf; one __syncthreads per step
// (its implicit vmcnt(0)+lgkmcnt(0) drain makes the flip race-free).
// EPI: 0 = fp32 out (+bias)
//      1 = fp32 out with key-mask -> -1e30 (scores)
//      2 = fp16 out (+bias)
//      4 = fp16 out TRANSPOSED per batch: VT[b][col][row&2047]  (+bias)
#define GLL(gp, ldsoff) \
  __builtin_amdgcn_global_load_lds((const __attribute__((address_space(1))) void*)(gp), \
                                   (__attribute__((address_space(3))) void*)&lds[ldsoff], 16, 0, 0)

template<int EPI>
__global__ __launch_bounds__(256)
void gemm_bt(const unsigned short* __restrict__ A, const unsigned short* __restrict__ B,
             int lda, int ldb, int K,
             const float* __restrict__ bias, const void* __restrict__ mask,
             const int* __restrict__ maskFlag,
             void* __restrict__ out0, int ldc,
             long aBS, long bBS, long oBS, int maskBS)
{
  // 2 buffers x (A 128x32 + B 128x32) fp16 = 2 x 16KB = 32KB
  __shared__ short lds[2 * 8192];

  const int z = blockIdx.z;
  const long zA = (long)z * aBS, zB = (long)z * bBS;
  const int tid = threadIdx.x;
  const int lane = tid & 63, wid = tid >> 6;
  const int wr = wid >> 1, wc = wid & 1;
  const int fr = lane & 15, fk = lane >> 4;
  const int brow = blockIdx.x * 128, bcol = blockIdx.y * 128;

  f32x4 acc[4][4];
  const f32x4 fzero = {0.f, 0.f, 0.f, 0.f};
#pragma unroll
  for (int i = 0; i < 4; i++)
#pragma unroll
    for (int j = 0; j < 4; j++) acc[i][j] = fzero;

  const int offA = (wr * 64 + fr) * 32 + fk * 8;   // element offset in A tile
  const int offB = (wc * 64 + fr) * 32 + fk * 8;   // element offset in B tile
  const int srow = tid >> 2;                       // staging row 0..63
  const int sck  = (tid & 3) * 8;                  // staging col (elements)

  const unsigned short* gA0 = A + zA + (long)(brow + srow) * lda + sck;
  const unsigned short* gB0 = B + zB + (long)(bcol + srow) * ldb + sck;
  const long a64 = (long)64 * lda, b64 = (long)64 * ldb;

#define STAGE(base, k0)                              \
  do {                                               \
    GLL(gA0 + (k0),       (base) + tid * 8);         \
    GLL(gA0 + (k0) + a64, (base) + (256 + tid) * 8); \
    GLL(gB0 + (k0),       (base) + 4096 + tid * 8);  \
    GLL(gB0 + (k0) + b64, (base) + 4096 + (256 + tid) * 8); \
  } while (0)

  const int nt = K >> 5;
  STAGE(0, 0);
  __syncthreads();          // drains vmcnt(0): buf0 ready

  int cur = 0;
  for (int t = 0; t < nt; ++t) {
    if (t + 1 < nt) STAGE((cur ^ 1) * 8192, (t + 1) << 5);  // prefetch into other buf

    const int ab = cur * 8192;
    half8 a[4], b[4];
#pragma unroll
    for (int i = 0; i < 4; i++){
      a[i] = *(const half8*)&lds[ab + offA + i * 512];
      b[i] = *(const half8*)&lds[ab + 4096 + offB + i * 512];
    }
#pragma unroll
    for (int mi = 0; mi < 4; mi++)
#pragma unroll
      for (int ni = 0; ni < 4; ni++)
        acc[mi][ni] = __builtin_amdgcn_mfma_f32_16x16x32_f16(a[mi], b[ni], acc[mi][ni], 0, 0, 0);

    __syncthreads();        // implicit vmcnt(0): prefetched buf landed; all reads of cur done
    cur ^= 1;
  }
#undef STAGE

  // epilogue: C/D frag layout col=lane&15, row=(lane>>4)*4+r  [m89-verified]
  const long zO = (long)z * oBS;
  int mflag = 0;
  if constexpr (EPI == 1) mflag = *maskFlag;
#pragma unroll
  for (int mi = 0; mi < 4; mi++){
#pragma unroll
    for (int ni = 0; ni < 4; ni++){
      const int col = bcol + wc * 64 + ni * 16 + fr;
      float bv = 0.f;
      if constexpr (EPI != 1) { if (bias) bv = bias[col]; }
      bool msk = false;
      if constexpr (EPI == 1) {
        msk = mflag ? (((const int*)mask)[(long)z * maskBS + col] != 0)
                    : (((const unsigned char*)mask)[(long)z * maskBS + col] != 0);
      }
#pragma unroll
      for (int r = 0; r < 4; r++){
        const int row = brow + wr * 64 + mi * 16 + fk * 4 + r;
        float v = acc[mi][ni][r] + bv;
        if constexpr (EPI == 0) {
          ((float*)out0)[zO + (long)row * ldc + col] = v;
        } else if constexpr (EPI == 1) {
          ((float*)out0)[zO + (long)row * ldc + col] = msk ? -1e30f : v;
        } else if constexpr (EPI == 2) {
          ((_Float16*)out0)[zO + (long)row * ldc + col] = (_Float16)v;
        } else {
          // transposed per-batch store: VT[b][col][t], b=row>>11, t=row&2047
          const int bb = row >> 11, t = row & 2047;
          ((_Float16*)out0)[(long)bb * 2048 * 1024 + (long)col * 2048 + t] = (_Float16)v;
        }
      }
    }
  }
}

extern "C" void kernel_launch(void* const* d_in, const int* in_sizes, int n_in,
                              void* d_out, int out_size, void* d_ws, size_t ws_size,
                              hipStream_t stream)
{
  (void)in_sizes; (void)n_in; (void)out_size; (void)ws_size;
  const float* query = (const float*)d_in[0];   // (4,2048,1024)
  const float* key   = (const float*)d_in[1];   // (4,2048,1024)
  const void*  kmask = d_in[2];                 // (4,2048) bool -> dtype detected on device
  const float* Wq    = (const float*)d_in[3];   // (1024,1024)
  const float* bq    = (const float*)d_in[4];
  const float* Wk    = (const float*)d_in[5];   // (2048,1024)
  const float* bk    = (const float*)d_in[6];
  const float* Wfc   = (const float*)d_in[7];   // (1024,1024)
  const float* bfc   = (const float*)d_in[8];
  float* out = (float*)d_out;

  char* ws = (char*)d_ws;
  size_t o = 0;
  auto take = [&](size_t bytes)->char*{
    char* p = ws + o;
    o += (bytes + 255) & ~(size_t)255;
    return p;
  };
  const size_t SZ_H = (size_t)8192 * 1024 * 2;      // 16.78 MB (8192x1024 fp16)

  int* maskFlag           = (int*)take(256);
  unsigned short* query_h = (unsigned short*)take(SZ_H);
  unsigned short* key_h   = (unsigned short*)take(SZ_H);
  unsigned short* Wq_h    = (unsigned short*)take((size_t)1024 * 1024 * 2);
  unsigned short* Wk_h    = (unsigned short*)take((size_t)2048 * 1024 * 2);
  unsigned short* Wfc_h   = (unsigned short*)take((size_t)1024 * 1024 * 2);
  unsigned short* Q       = (unsigned short*)take(SZ_H);
  unsigned short* K       = (unsigned short*)take(SZ_H);
  unsigned short* VT      = (unsigned short*)take(SZ_H);
  unsigned short* O       = (unsigned short*)take(SZ_H);
  float*          S       = (float*)take((size_t)8192 * 2048 * 4);   // 67.1 MB
  unsigned short* P       = (unsigned short*)take((size_t)8192 * 2048 * 2); // 33.6 MB

  mask_detect<<<1, 64, 0, stream>>>((const unsigned int*)kmask, maskFlag);

  conv4_k<<<8192, 256, 0, stream>>>((const float4*)query, (half4*)query_h);
  conv4_k<<<8192, 256, 0, stream>>>((const float4*)key,   (half4*)key_h);
  conv4_k<<<1024, 256, 0, stream>>>((const float4*)Wq,    (half4*)Wq_h);
  conv4_k<<<2048, 256, 0, stream>>>((const float4*)Wk,    (half4*)Wk_h);
  conv4_k<<<1024, 256, 0, stream>>>((const float4*)Wfc,   (half4*)Wfc_h);

  // Q = query @ Wq^T + bq   (8192x1024, K=1024) -> fp16
  gemm_bt<2><<<dim3(64, 8, 1), 256, 0, stream>>>(
      query_h, Wq_h, 1024, 1024, 1024,
      bq, nullptr, nullptr, Q, 1024, 0, 0, 0, 0);

  // K = key @ Wk[0:1024]^T + bk[0:1024] -> fp16
  gemm_bt<2><<<dim3(64, 8, 1), 256, 0, stream>>>(
      key_h, Wk_h, 1024, 1024, 1024,
      bk, nullptr, nullptr, K, 1024, 0, 0, 0, 0);

  // V = key @ Wk[1024:2048]^T + bk[1024:2048] -> VT (transposed per batch) fp16
  gemm_bt<4><<<dim3(64, 8, 1), 256, 0, stream>>>(
      key_h, Wk_h + (size_t)1024 * 1024, 1024, 1024, 1024,
      bk + 1024, nullptr, nullptr, VT, 0, 0, 0, 0, 0);

  // scores: per batch S = Q @ K^T, masked  (2048x2048, K=1024) -> fp32
  gemm_bt<1><<<dim3(16, 16, 4), 256, 0, stream>>>(
      Q, K, 1024, 1024, 1024,
      nullptr, kmask, maskFlag, S, 2048,
      (long)2048 * 1024, (long)2048 * 1024, (long)2048 * 2048, 2048);

  softmax2048<<<8192, 256, 0, stream>>>(S, (_Float16*)P);

  // O = P @ V  (per batch 2048x1024, K=2048; B = VT) -> fp16
  gemm_bt<2><<<dim3(16, 8, 4), 256, 0, stream>>>(
      P, VT, 2048, 2048, 2048,
      nullptr, nullptr, nullptr, O, 1024,
      (long)2048 * 2048, (long)1024 * 2048, (long)2048 * 1024, 0);

  // out = O @ Wfc^T + bfc  (8192x1024, K=1024) -> fp32
  gemm_bt<0><<<dim3(64, 8, 1), 256, 0, stream>>>(
      O, Wfc_h, 1024, 1024, 1024,
      bfc, nullptr, nullptr, out, 1024, 0, 0, 0, 0);
}